// Round 15
// baseline (29.153 us; speedup 1.0000x reference)
//
#include <hip/hip_runtime.h>
#include <hip/hip_bf16.h>
#include <math.h>

#define HH 768
#define NB 8
#define LL 256
#define MM 128
#define NROW1 (NB*MM)        // 1024 dns rows
#define NROW2 (NB*LL)        // 2048 text rows
#define NROWS (NROW1+NROW2)  // 3072
#define NCB 12               // 768/64 column blocks

typedef __attribute__((ext_vector_type(8))) short  bf16x8;
typedef __attribute__((ext_vector_type(4))) float  f32x4;

static __device__ __forceinline__ unsigned int pkbf2(float a, float b) {
    __hip_bfloat162 h = __float22bfloat162_rn(make_float2(a, b));
    unsigned int u; __builtin_memcpy(&u, &h, 4); return u;
}

static __device__ __forceinline__ float fast_tanh(float x) {
    float e = __expf(2.0f * x);
    return 1.0f - 2.0f * __builtin_amdgcn_rcpf(e + 1.0f);
}

// async global->LDS DMA, 16B per lane (r13/r14-proven).
static __device__ __forceinline__ void gload_lds16(const void* g, void* l) {
    __builtin_amdgcn_global_load_lds(
        (const __attribute__((address_space(1))) unsigned int*)g,
        (__attribute__((address_space(3))) unsigned int*)l, 16, 0, 0);
}

// ---------------------------------------------------------------------------
// One-shot fp32 -> bf16 conversion of all GEMM operands. (verbatim r4-r14)
// ---------------------------------------------------------------------------
__global__ __launch_bounds__(256) void prep_bf16(
    const float4* __restrict__ text, const float4* __restrict__ dns,
    const float4* __restrict__ Wd1, const float4* __restrict__ Wt2,
    uint2* __restrict__ Xb, uint2* __restrict__ Wb)
{
    const int i = blockIdx.x * 256 + threadIdx.x;   // 884736 threads exactly
    const float4* src; uint2* dst;
    if (i < 589824) {
        dst = Xb + i;
        src = (i < 196608) ? (dns + i) : (text + (i - 196608));
    } else {
        dst = Wb + (i - 589824);
        src = (i < 737280) ? (Wd1 + (i - 589824)) : (Wt2 + (i - 737280));
    }
    float4 v = *src;
    uint2 o; o.x = pkbf2(v.x, v.y); o.y = pkbf2(v.z, v.w);
    *dst = o;
}

// ---------------------------------------------------------------------------
// Score GEMM v9: r14's gload_lds16 + counted vmcnt, but DOUBLE-buffered
// (32 KB LDS -> 5 blocks/CU = 5 waves/SIMD, 2.2x r14's TLP; r14 was 48 KB ->
// 2.25 blocks/CU avg). Per iter: barrier (all waves done reading buf
// (k+1)&1 in iter k-1 -> write-after-read safe) ; STAGE(k+1) into that buf ;
// vmcnt(4) (tile k's 4 DMAs landed, k+1's 4 stay in flight) ; MFMA(k).
// Depth 1 tile (~360 CU-cyc cover) + 5 waves/SIMD TLP covers L2 latency.
// STAGE/MFMA bodies verbatim r14 -> bit-identical numerics.
// ---------------------------------------------------------------------------
__global__ __launch_bounds__(256) void score_mfma(
    const unsigned short* __restrict__ Xb, const unsigned short* __restrict__ Wb,
    const float* __restrict__ wv1, const float* __restrict__ wv2,
    float* __restrict__ partial)
{
    __shared__ __align__(16) unsigned short A2[2][64 * 64];   // 16 KB
    __shared__ __align__(16) unsigned short B2[2][64 * 64];   // 16 KB

    const int t = threadIdx.x;
    const int tile = (blockIdx.x >> 3) + (blockIdx.x & 7) * 72;  // 576 = 8*72
    const int rb = tile / 12, cb = tile % 12;
    const int row0 = rb * 64, col0 = cb * 64;

    const unsigned short* X = Xb + (size_t)row0 * HH;
    const unsigned short* W; const float* wv;
    if (row0 < NROW1) { W = Wb;                    wv = wv1; }
    else              { W = Wb + (size_t)HH * HH;  wv = wv2; }

    const int l  = t & 63;
    const int w  = t >> 6;
    const int wr = w * 16;        // this wave's 16 output rows
    const int lc = l & 15;

    // staging geometry (verbatim r13/r14): lane i stages row w*16 + (i>>3),
    // stored chunk i&7, global chunk (i&7)^(i>>3).
    const int roff = l >> 3;                    // 0..7
    const int gch  = ((l & 7) ^ roff) * 8;      // swizzled global k offset
    const int rA0  = w * 16 + roff;
    const unsigned short* apx = X + (size_t)rA0 * HH + gch;
    const unsigned short* bpx = W + (size_t)(col0 + rA0) * HH + gch;

    f32x4 acc[4] = {};

    auto STAGE = [&](int buf, int k0) {
        unsigned short* Abase = &A2[buf][(w * 16) * 64];
        unsigned short* Bbase = &B2[buf][(w * 16) * 64];
        gload_lds16(apx + k0,            Abase);
        gload_lds16(apx + 8 * HH + k0,   Abase + 8 * 64);
        gload_lds16(bpx + k0,            Bbase);
        gload_lds16(bpx + 8 * HH + k0,   Bbase + 8 * 64);
    };

    auto MFMA_TILE = [&](int buf) {
        #pragma unroll
        for (int kk = 0; kk < 2; ++kk) {
            const int C = kk * 4 + (l >> 4);                 // k-chunk 0..7
            const int sw = (C ^ (lc & 7)) * 8;               // swizzled chunk
            bf16x8 a = *reinterpret_cast<const bf16x8*>(&A2[buf][(wr + lc) * 64 + sw]);
            #pragma unroll
            for (int n = 0; n < 4; ++n) {
                bf16x8 b = *reinterpret_cast<const bf16x8*>(&B2[buf][(n * 16 + lc) * 64 + sw]);
                acc[n] = __builtin_amdgcn_mfma_f32_16x16x32_bf16(a, b, acc[n], 0, 0, 0);
            }
        }
    };

    // prologue: tile 0 in flight
    STAGE(0, 0);

    #pragma unroll 1
    for (int k = 0; k < 12; ++k) {
        __builtin_amdgcn_s_barrier();         // all waves done reading buf (k+1)&1
        if (k < 11) {
            STAGE((k + 1) & 1, (k + 1) * 64); // overwrite the just-freed buffer
            asm volatile("s_waitcnt vmcnt(4)" ::: "memory");   // tile k landed
        } else {
            asm volatile("s_waitcnt vmcnt(0)" ::: "memory");
        }
        __builtin_amdgcn_s_barrier();         // tile k visible to all waves
        MFMA_TILE(k & 1);
        __builtin_amdgcn_sched_barrier(0);    // keep reads inside the phase
    }

    // epilogue (verbatim r7): tanh * wvec over 64 cols, 16-lane reduce
    float wvn[4];
    #pragma unroll
    for (int n = 0; n < 4; ++n) wvn[n] = wv[col0 + n*16 + lc];
    #pragma unroll
    for (int i = 0; i < 4; ++i) {
        float s = 0.f;
        #pragma unroll
        for (int n = 0; n < 4; ++n) s += fast_tanh(acc[n][i]) * wvn[n];
        s += __shfl_xor(s, 1);
        s += __shfl_xor(s, 2);
        s += __shfl_xor(s, 4);
        s += __shfl_xor(s, 8);
        if (lc == 0)
            partial[(size_t)(row0 + wr + (l >> 4)*4 + i) * NCB + cb] = s;
    }
}

// ---------------------------------------------------------------------------
// Fused tail (verbatim r7): softmax from L2-hot partials + weighted sums +
// broadcast write. Grid (8, 48), 256 threads.
// ---------------------------------------------------------------------------
__global__ __launch_bounds__(256) void tail_kernel(
    const float* __restrict__ text, const float* __restrict__ dns,
    const float* __restrict__ partial, float* __restrict__ out)
{
    const int b = blockIdx.x, hc = blockIdx.y;   // hc 0..47
    const int t = threadIdx.x;
    __shared__ float p1s[128], p2s[256], red[8];
    __shared__ __align__(16) float bt[256], bd[256];

    if (t < 128) {
        const float* pr = partial + (size_t)(b * MM + t) * NCB;
        float s = 0.f;
        #pragma unroll
        for (int c = 0; c < NCB; ++c) s += pr[c];
        p1s[t] = s;
    }
    {
        const float* pr = partial + (size_t)(NROW1 + b * LL + t) * NCB;
        float s = 0.f;
        #pragma unroll
        for (int c = 0; c < NCB; ++c) s += pr[c];
        p2s[t] = s;
    }
    __syncthreads();

    float x1 = (t < 128) ? p1s[t] : -1e30f;
    float m1 = x1;
    #pragma unroll
    for (int d = 1; d < 64; d <<= 1) m1 = fmaxf(m1, __shfl_xor(m1, d));
    if ((t & 63) == 0) red[t >> 6] = m1;
    float x2 = p2s[t];
    float m2 = x2;
    #pragma unroll
    for (int d = 1; d < 64; d <<= 1) m2 = fmaxf(m2, __shfl_xor(m2, d));
    if ((t & 63) == 0) red[4 + (t >> 6)] = m2;
    __syncthreads();
    m1 = fmaxf(fmaxf(red[0], red[1]), fmaxf(red[2], red[3]));
    m2 = fmaxf(fmaxf(red[4], red[5]), fmaxf(red[6], red[7]));

    float e1 = (t < 128) ? __expf(x1 - m1) : 0.f;
    float e2 = __expf(x2 - m2);
    __syncthreads();
    float s1 = e1, s2 = e2;
    #pragma unroll
    for (int d = 1; d < 64; d <<= 1) { s1 += __shfl_xor(s1, d); s2 += __shfl_xor(s2, d); }
    if ((t & 63) == 0) { red[t >> 6] = s1; red[4 + (t >> 6)] = s2; }
    __syncthreads();
    s1 = red[0] + red[1] + red[2] + red[3];
    s2 = red[4] + red[5] + red[6] + red[7];
    if (t < 128) p1s[t] = e1 / s1;
    p2s[t] = e2 / s2;
    __syncthreads();

    const int hh  = hc * 16 + (t & 15);
    const int rsl = t >> 4;                      // 0..15 row-slices

    const int jr0 = rsl * 16;                    // 16 text rows per slice
    float st = 0.f;
    #pragma unroll
    for (int r = 0; r < 16; ++r)
        st = fmaf(p2s[jr0 + r], text[(size_t)(b * LL + jr0 + r) * HH + hh], st);

    const int mr0 = rsl * 8;                     // 8 dns rows per slice
    float sd = 0.f;
    #pragma unroll
    for (int r = 0; r < 8; ++r)
        sd = fmaf(p1s[mr0 + r], dns[(size_t)(b * MM + mr0 + r) * HH + hh], sd);

    bt[t] = st; bd[t] = sd;
    __syncthreads();
    if (t < 128) { bt[t] += bt[t + 128]; bd[t] += bd[t + 128]; } __syncthreads();
    if (t < 64)  { bt[t] += bt[t + 64];  bd[t] += bd[t + 64];  } __syncthreads();
    if (t < 32)  { bt[t] += bt[t + 32];  bd[t] += bd[t + 32];  } __syncthreads();
    if (t < 16)  { bt[t] += bt[t + 16];  bd[t] += bd[t + 16];  }
    __syncthreads();

    const int H4 = HH / 4;                       // 192
    const int n4out = NB * LL * H4;              // 393216
    const float4* svt4 = reinterpret_cast<const float4*>(bt);
    const float4* svd4 = reinterpret_cast<const float4*>(bd);
    float4* out4 = reinterpret_cast<float4*>(out);
    #pragma unroll
    for (int i = t; i < LL * 4; i += 256) {      // 1024 = 256 rows x 4 f4
        const int ll = i >> 2, c4 = i & 3;
        const size_t o = (size_t)(b * LL + ll) * H4 + hc * 4 + c4;
        out4[o] = svt4[c4];
        out4[n4out + o] = svd4[c4];
    }
}

extern "C" void kernel_launch(void* const* d_in, const int* in_sizes, int n_in,
                              void* d_out, int out_size, void* d_ws, size_t ws_size,
                              hipStream_t stream) {
    const float* text   = (const float*)d_in[0];   // (8,256,768)
    const float* dns    = (const float*)d_in[1];   // (8,128,768)
    const float* W_d1   = (const float*)d_in[4];   // (768,768)
    const float* w_att1 = (const float*)d_in[5];   // (1536,)
    const float* W_t2   = (const float*)d_in[9];   // (768,768)
    const float* w_att2 = (const float*)d_in[10];  // (1536,)

    float* ws      = (float*)d_ws;
    float* partial = ws;                                   // 36864 f
    unsigned short* Xb = (unsigned short*)(ws + 36864);    // 2359296 bf16
    unsigned short* Wb = Xb + (size_t)NROWS * HH;          // 1179648 bf16
    float* out     = (float*)d_out;

    prep_bf16<<<3456, 256, 0, stream>>>(
        (const float4*)text, (const float4*)dns, (const float4*)W_d1,
        (const float4*)W_t2, (uint2*)Xb, (uint2*)Wb);
    score_mfma<<<576, 256, 0, stream>>>(
        Xb, Wb, w_att1 + HH, w_att2 + HH, partial);
    tail_kernel<<<dim3(NB, 48), 256, 0, stream>>>(text, dns, partial, out);
}

// Round 16
// 29.086 us; speedup vs baseline: 1.0023x; 1.0023x over previous
//
#include <hip/hip_runtime.h>
#include <hip/hip_bf16.h>
#include <math.h>

#define HH 768
#define NB 8
#define LL 256
#define MM 128
#define NROW1 (NB*MM)        // 1024 dns rows
#define NROW2 (NB*LL)        // 2048 text rows
#define NROWS (NROW1+NROW2)  // 3072
#define NCB 12               // 768/64 column blocks

typedef __attribute__((ext_vector_type(8))) short  bf16x8;
typedef __attribute__((ext_vector_type(4))) float  f32x4;

static __device__ __forceinline__ unsigned int pkbf2(float a, float b) {
    __hip_bfloat162 h = __float22bfloat162_rn(make_float2(a, b));
    unsigned int u; __builtin_memcpy(&u, &h, 4); return u;
}

static __device__ __forceinline__ float fast_tanh(float x) {
    float e = __expf(2.0f * x);
    return 1.0f - 2.0f * __builtin_amdgcn_rcpf(e + 1.0f);
}

// async global->LDS DMA, 16B per lane (r13/r14-proven).
static __device__ __forceinline__ void gload_lds16(const void* g, void* l) {
    __builtin_amdgcn_global_load_lds(
        (const __attribute__((address_space(1))) unsigned int*)g,
        (__attribute__((address_space(3))) unsigned int*)l, 16, 0, 0);
}

// ---------------------------------------------------------------------------
// One-shot fp32 -> bf16 conversion of all GEMM operands. (verbatim r4-r15)
// ---------------------------------------------------------------------------
__global__ __launch_bounds__(256) void prep_bf16(
    const float4* __restrict__ text, const float4* __restrict__ dns,
    const float4* __restrict__ Wd1, const float4* __restrict__ Wt2,
    uint2* __restrict__ Xb, uint2* __restrict__ Wb)
{
    const int i = blockIdx.x * 256 + threadIdx.x;   // 884736 threads exactly
    const float4* src; uint2* dst;
    if (i < 589824) {
        dst = Xb + i;
        src = (i < 196608) ? (dns + i) : (text + (i - 196608));
    } else {
        dst = Wb + (i - 589824);
        src = (i < 737280) ? (Wd1 + (i - 589824)) : (Wt2 + (i - 737280));
    }
    float4 v = *src;
    uint2 o; o.x = pkbf2(v.x, v.y); o.y = pkbf2(v.z, v.w);
    *dst = o;
}

// ---------------------------------------------------------------------------
// Score GEMM v10: r14's proven {3-buffer, 1 barrier/iter, counted vmcnt}
// schedule with a 128row x 64col block (512 thr, 8 waves). B-tile shared by
// 8 waves -> W traffic halves (110 -> 83 MB total); 64 MFMAs/block/period
// amortize each barrier over ~2x compute; 288 blocks (= 8*36, bijective
// XCD swizzle). Per-wave row/col partition and MFMA order are IDENTICAL to
// r14 (wave w owns global rows rb*128 + w*16) -> bit-identical numerics.
// DMAs/wave/tile = 3 (2xA, 1xB) -> vmcnt(3) = tile k landed, k+1 in flight.
// LDS 72 KB -> 2 blocks/CU.
// ---------------------------------------------------------------------------
__global__ __launch_bounds__(512) void score_mfma(
    const unsigned short* __restrict__ Xb, const unsigned short* __restrict__ Wb,
    const float* __restrict__ wv1, const float* __restrict__ wv2,
    float* __restrict__ partial)
{
    __shared__ __align__(16) unsigned short A3[3][128 * 64];  // 48 KB
    __shared__ __align__(16) unsigned short B3[3][64 * 64];   // 24 KB

    const int t = threadIdx.x;
    const int tile = (blockIdx.x >> 3) + (blockIdx.x & 7) * 36;  // 288 = 8*36
    const int rb = tile / 12, cb = tile % 12;
    const int row0 = rb * 128, col0 = cb * 64;

    const unsigned short* X = Xb + (size_t)row0 * HH;
    const unsigned short* W; const float* wv;
    if (row0 < NROW1) { W = Wb;                    wv = wv1; }
    else              { W = Wb + (size_t)HH * HH;  wv = wv2; }

    const int l  = t & 63;
    const int w  = t >> 6;        // 0..7
    const int wr = w * 16;        // this wave's 16 rows within the 128-row tile
    const int lc = l & 15;

    // staging geometry (r13/r14 pattern): lane i stages row base + (i>>3),
    // stored chunk i&7, global chunk (i&7)^(i>>3).
    const int roff = l >> 3;                    // 0..7
    const int gch  = ((l & 7) ^ roff) * 8;      // swizzled global k offset
    const unsigned short* apx = X + (size_t)(wr + roff) * HH + gch;
    const unsigned short* bpx = W + (size_t)(col0 + w * 8 + roff) * HH + gch;

    f32x4 acc[4] = {};

    auto STAGE = [&](int buf, int k0) {
        unsigned short* Abase = &A3[buf][wr * 64];
        unsigned short* Bbase = &B3[buf][(w * 8) * 64];
        gload_lds16(apx + k0,            Abase);            // A rows wr..wr+8
        gload_lds16(apx + 8 * HH + k0,   Abase + 8 * 64);   // A rows wr+8..+16
        gload_lds16(bpx + k0,            Bbase);            // B rows w*8..+8
    };

    auto MFMA_TILE = [&](int buf) {
        #pragma unroll
        for (int kk = 0; kk < 2; ++kk) {
            const int C = kk * 4 + (l >> 4);                 // k-chunk 0..7
            const int sw = (C ^ (lc & 7)) * 8;               // swizzled chunk
            bf16x8 a = *reinterpret_cast<const bf16x8*>(&A3[buf][(wr + lc) * 64 + sw]);
            #pragma unroll
            for (int n = 0; n < 4; ++n) {
                bf16x8 b = *reinterpret_cast<const bf16x8*>(&B3[buf][(n * 16 + lc) * 64 + sw]);
                acc[n] = __builtin_amdgcn_mfma_f32_16x16x32_bf16(a, b, acc[n], 0, 0, 0);
            }
        }
    };

    // prologue: tiles 0,1 in flight (6 DMAs/wave outstanding)
    STAGE(0, 0);
    STAGE(1, 64);

    #pragma unroll 1
    for (int k = 0; k < 12; ++k) {
        if (k < 11) asm volatile("s_waitcnt vmcnt(3)" ::: "memory");
        else        asm volatile("s_waitcnt vmcnt(0)" ::: "memory");
        __builtin_amdgcn_s_barrier();         // tile k landed in ALL waves
        MFMA_TILE(k % 3);
        __builtin_amdgcn_sched_barrier(0);    // pin reads before next DMAs
        if (k < 10) STAGE((k + 2) % 3, (k + 2) * 64);
    }

    // epilogue (verbatim r7/r14): tanh * wvec over 64 cols, 16-lane reduce
    float wvn[4];
    #pragma unroll
    for (int n = 0; n < 4; ++n) wvn[n] = wv[col0 + n*16 + lc];
    #pragma unroll
    for (int i = 0; i < 4; ++i) {
        float s = 0.f;
        #pragma unroll
        for (int n = 0; n < 4; ++n) s += fast_tanh(acc[n][i]) * wvn[n];
        s += __shfl_xor(s, 1);
        s += __shfl_xor(s, 2);
        s += __shfl_xor(s, 4);
        s += __shfl_xor(s, 8);
        if (lc == 0)
            partial[(size_t)(row0 + wr + (l >> 4)*4 + i) * NCB + cb] = s;
    }
}

// ---------------------------------------------------------------------------
// Fused tail (verbatim r7): softmax from L2-hot partials + weighted sums +
// broadcast write. Grid (8, 48), 256 threads.
// ---------------------------------------------------------------------------
__global__ __launch_bounds__(256) void tail_kernel(
    const float* __restrict__ text, const float* __restrict__ dns,
    const float* __restrict__ partial, float* __restrict__ out)
{
    const int b = blockIdx.x, hc = blockIdx.y;   // hc 0..47
    const int t = threadIdx.x;
    __shared__ float p1s[128], p2s[256], red[8];
    __shared__ __align__(16) float bt[256], bd[256];

    if (t < 128) {
        const float* pr = partial + (size_t)(b * MM + t) * NCB;
        float s = 0.f;
        #pragma unroll
        for (int c = 0; c < NCB; ++c) s += pr[c];
        p1s[t] = s;
    }
    {
        const float* pr = partial + (size_t)(NROW1 + b * LL + t) * NCB;
        float s = 0.f;
        #pragma unroll
        for (int c = 0; c < NCB; ++c) s += pr[c];
        p2s[t] = s;
    }
    __syncthreads();

    float x1 = (t < 128) ? p1s[t] : -1e30f;
    float m1 = x1;
    #pragma unroll
    for (int d = 1; d < 64; d <<= 1) m1 = fmaxf(m1, __shfl_xor(m1, d));
    if ((t & 63) == 0) red[t >> 6] = m1;
    float x2 = p2s[t];
    float m2 = x2;
    #pragma unroll
    for (int d = 1; d < 64; d <<= 1) m2 = fmaxf(m2, __shfl_xor(m2, d));
    if ((t & 63) == 0) red[4 + (t >> 6)] = m2;
    __syncthreads();
    m1 = fmaxf(fmaxf(red[0], red[1]), fmaxf(red[2], red[3]));
    m2 = fmaxf(fmaxf(red[4], red[5]), fmaxf(red[6], red[7]));

    float e1 = (t < 128) ? __expf(x1 - m1) : 0.f;
    float e2 = __expf(x2 - m2);
    __syncthreads();
    float s1 = e1, s2 = e2;
    #pragma unroll
    for (int d = 1; d < 64; d <<= 1) { s1 += __shfl_xor(s1, d); s2 += __shfl_xor(s2, d); }
    if ((t & 63) == 0) { red[t >> 6] = s1; red[4 + (t >> 6)] = s2; }
    __syncthreads();
    s1 = red[0] + red[1] + red[2] + red[3];
    s2 = red[4] + red[5] + red[6] + red[7];
    if (t < 128) p1s[t] = e1 / s1;
    p2s[t] = e2 / s2;
    __syncthreads();

    const int hh  = hc * 16 + (t & 15);
    const int rsl = t >> 4;                      // 0..15 row-slices

    const int jr0 = rsl * 16;                    // 16 text rows per slice
    float st = 0.f;
    #pragma unroll
    for (int r = 0; r < 16; ++r)
        st = fmaf(p2s[jr0 + r], text[(size_t)(b * LL + jr0 + r) * HH + hh], st);

    const int mr0 = rsl * 8;                     // 8 dns rows per slice
    float sd = 0.f;
    #pragma unroll
    for (int r = 0; r < 8; ++r)
        sd = fmaf(p1s[mr0 + r], dns[(size_t)(b * MM + mr0 + r) * HH + hh], sd);

    bt[t] = st; bd[t] = sd;
    __syncthreads();
    if (t < 128) { bt[t] += bt[t + 128]; bd[t] += bd[t + 128]; } __syncthreads();
    if (t < 64)  { bt[t] += bt[t + 64];  bd[t] += bd[t + 64];  } __syncthreads();
    if (t < 32)  { bt[t] += bt[t + 32];  bd[t] += bd[t + 32];  } __syncthreads();
    if (t < 16)  { bt[t] += bt[t + 16];  bd[t] += bd[t + 16];  }
    __syncthreads();

    const int H4 = HH / 4;                       // 192
    const int n4out = NB * LL * H4;              // 393216
    const float4* svt4 = reinterpret_cast<const float4*>(bt);
    const float4* svd4 = reinterpret_cast<const float4*>(bd);
    float4* out4 = reinterpret_cast<float4*>(out);
    #pragma unroll
    for (int i = t; i < LL * 4; i += 256) {      // 1024 = 256 rows x 4 f4
        const int ll = i >> 2, c4 = i & 3;
        const size_t o = (size_t)(b * LL + ll) * H4 + hc * 4 + c4;
        out4[o] = svt4[c4];
        out4[n4out + o] = svd4[c4];
    }
}

extern "C" void kernel_launch(void* const* d_in, const int* in_sizes, int n_in,
                              void* d_out, int out_size, void* d_ws, size_t ws_size,
                              hipStream_t stream) {
    const float* text   = (const float*)d_in[0];   // (8,256,768)
    const float* dns    = (const float*)d_in[1];   // (8,128,768)
    const float* W_d1   = (const float*)d_in[4];   // (768,768)
    const float* w_att1 = (const float*)d_in[5];   // (1536,)
    const float* W_t2   = (const float*)d_in[9];   // (768,768)
    const float* w_att2 = (const float*)d_in[10];  // (1536,)

    float* ws      = (float*)d_ws;
    float* partial = ws;                                   // 36864 f
    unsigned short* Xb = (unsigned short*)(ws + 36864);    // 2359296 bf16
    unsigned short* Wb = Xb + (size_t)NROWS * HH;          // 1179648 bf16
    float* out     = (float*)d_out;

    prep_bf16<<<3456, 256, 0, stream>>>(
        (const float4*)text, (const float4*)dns, (const float4*)W_d1,
        (const float4*)W_t2, (uint2*)Xb, (uint2*)Wb);
    score_mfma<<<288, 512, 0, stream>>>(
        Xb, Wb, w_att1 + HH, w_att2 + HH, partial);
    tail_kernel<<<dim3(NB, 48), 256, 0, stream>>>(text, dns, partial, out);
}